// Round 3
// baseline (192.299 us; speedup 1.0000x reference)
//
#include <hip/hip_runtime.h>
#include <hip/hip_bf16.h>

// InfoNCE (n_views=1): loss = mean_i [ LSE_{j!=i}(f_i . f_j / T) - f_i . f_{c_i} / T ].
// Upper-triangle bf16 MFMA F F^T with fused FIXED-MAX softmax partials:
// since f rows are unit-norm, logit <= 1/T always, so exp(logit - 1/T) needs no
// online max. Each tile element is exp'd ONCE (in-place over acc regs) and the
// result feeds both the row-sum and (off-diag tiles) the col-sum partials.

typedef __bf16 bf16x8 __attribute__((ext_vector_type(8)));
typedef float f32x4 __attribute__((ext_vector_type(4)));

#define AS1 __attribute__((address_space(1)))
#define AS3 __attribute__((address_space(3)))

constexpr int NB = 8192;   // batch
constexpr int ND = 512;    // dim
constexpr float INV_T = 1.0f / 0.07f;

__device__ inline unsigned short f2bf(float f) {
    union { float f; unsigned int u; } v; v.f = f;
    unsigned int u = v.u;
    u = u + 0x7fffu + ((u >> 16) & 1u);   // round-to-nearest-even
    return (unsigned short)(u >> 16);
}
__device__ inline float bf2f(unsigned short s) {
    union { unsigned int u; float f; } v; v.u = ((unsigned int)s) << 16;
    return v.f;
}

// ---------------- Kernel 1: normalize rows, fp32 -> bf16 feats; zero accum/ticket --
__global__ __launch_bounds__(256) void norm_kernel(const float* __restrict__ x,
                                                   unsigned short* __restrict__ feats,
                                                   float* __restrict__ accum,
                                                   unsigned int* __restrict__ ticket) {
    if (blockIdx.x == 0 && threadIdx.x == 0) { accum[0] = 0.0f; ticket[0] = 0u; }
    const int wave = threadIdx.x >> 6;
    const int lane = threadIdx.x & 63;
    const int row = blockIdx.x * 4 + wave;
    const float4* xr = (const float4*)(x + (size_t)row * ND);
    float4 a = xr[lane];        // cols 4*lane .. +3
    float4 b = xr[64 + lane];   // cols 256+4*lane .. +3
    float ss = a.x*a.x + a.y*a.y + a.z*a.z + a.w*a.w
             + b.x*b.x + b.y*b.y + b.z*b.z + b.w*b.w;
    #pragma unroll
    for (int m = 32; m >= 1; m >>= 1) ss += __shfl_xor(ss, m);
    float norm = sqrtf(ss);
    float scale = 1.0f / fmaxf(norm, 1e-12f);
    ushort4 o1, o2;
    o1.x = f2bf(a.x * scale); o1.y = f2bf(a.y * scale);
    o1.z = f2bf(a.z * scale); o1.w = f2bf(a.w * scale);
    o2.x = f2bf(b.x * scale); o2.y = f2bf(b.y * scale);
    o2.z = f2bf(b.z * scale); o2.w = f2bf(b.w * scale);
    ushort4* fr = (ushort4*)(feats + (size_t)row * ND);
    fr[lane]      = o1;
    fr[64 + lane] = o2;
}

// ---------------- Kernel 2: upper-tri 128x128 tiles, fused fixed-max sumexp --------
// 1D grid of 2080 blocks -> (bi <= bj). 256 threads = 4 waves (2x2 quadrants of
// 64x64). LDS rows 64 bf16 (128 B), XOR-swizzled (k8 ^= row&7): 0 bank conflicts.
__global__ __launch_bounds__(256) void sim_lse_kernel(const unsigned short* __restrict__ feats,
                                                      float* __restrict__ partials) {
    __shared__ unsigned short sA[128 * 64];
    __shared__ unsigned short sB[128 * 64];

    const int tid  = threadIdx.x;
    const int lane = tid & 63;
    const int wave = tid >> 6;
    const int wr   = wave >> 1;     // wave row quadrant (0..1)
    const int wc   = wave & 1;      // wave col quadrant (0..1)

    // decode upper-triangle pair: t -> (bi <= bj)
    int t = blockIdx.x;
    int bj = (int)((sqrtf(8.0f * (float)t + 1.0f) - 1.0f) * 0.5f);
    while ((bj + 1) * (bj + 2) / 2 <= t) ++bj;
    while (bj * (bj + 1) / 2 > t) --bj;
    const int bi = t - bj * (bj + 1) / 2;

    const int rowA0 = bi * 128;
    const int rowB0 = bj * 128;

    f32x4 acc[4][4] = {};

    const int m    = lane & 15;
    const int quad = lane >> 4;
    const int sw   = m & 7;         // ds_read swizzle term (row & 7 == m & 7)

    for (int kt = 0; kt < 8; ++kt) {
        const int k0 = kt * 64;
        #pragma unroll
        for (int r = 0; r < 4; ++r) {
            int c   = r * 256 + tid;        // 16B chunk id
            int row = c >> 3;
            int k8g = (c & 7) ^ (row & 7);
            const unsigned short* ga = feats + (size_t)(rowA0 + row) * ND + k0 + k8g * 8;
            const unsigned short* gb = feats + (size_t)(rowB0 + row) * ND + k0 + k8g * 8;
            __builtin_amdgcn_global_load_lds((const AS1 void*)ga, (AS3 void*)(sA + c * 8), 16, 0, 0);
            __builtin_amdgcn_global_load_lds((const AS1 void*)gb, (AS3 void*)(sB + c * 8), 16, 0, 0);
        }
        __syncthreads();
        #pragma unroll
        for (int ks = 0; ks < 2; ++ks) {
            const int k8 = ks * 4 + quad;   // logical 16B chunk within the row
            bf16x8 afrag[4], bfrag[4];
            #pragma unroll
            for (int s = 0; s < 4; ++s) {
                afrag[s] = *(const bf16x8*)(sA + (wr * 64 + s * 16 + m) * 64 + ((k8 ^ sw) << 3));
                bfrag[s] = *(const bf16x8*)(sB + (wc * 64 + s * 16 + m) * 64 + ((k8 ^ sw) << 3));
            }
            #pragma unroll
            for (int si = 0; si < 4; ++si)
                #pragma unroll
                for (int sj = 0; sj < 4; ++sj)
                    acc[si][sj] = __builtin_amdgcn_mfma_f32_16x16x32_bf16(
                        afrag[si], bfrag[sj], acc[si][sj], 0, 0, 0);
        }
        __syncthreads();
    }

    // ---- Transform in place: acc <- exp((sim-1)/T), diagonal -> 0 ----
    // C/D layout (16x16x32): col = lane&15, row = quad*4 + reg.
    const float C1 = INV_T * 1.4426950408889634f;   // log2(e)/T
    #pragma unroll
    for (int si = 0; si < 4; ++si) {
        #pragma unroll
        for (int sj = 0; sj < 4; ++sj) {
            const int gcol = rowB0 + wc * 64 + sj * 16 + m;
            #pragma unroll
            for (int r = 0; r < 4; ++r) {
                const int grow = rowA0 + wr * 64 + si * 16 + quad * 4 + r;
                float e = exp2f(fmaf(acc[si][sj][r], C1, -C1));
                acc[si][sj][r] = (grow == gcol) ? 0.0f : e;
            }
        }
    }

    // ---- Row pass: per-row sumexp over this wave's 64 cols ----
    #pragma unroll
    for (int si = 0; si < 4; ++si) {
        #pragma unroll
        for (int r = 0; r < 4; ++r) {
            float s = acc[si][0][r] + acc[si][1][r] + acc[si][2][r] + acc[si][3][r];
            #pragma unroll
            for (int msk = 1; msk < 16; msk <<= 1) s += __shfl_xor(s, msk);
            if (m == 0) {
                const int grow = rowA0 + wr * 64 + si * 16 + quad * 4 + r;
                partials[(size_t)grow * 128 + bj * 2 + wc] = s;
            }
        }
    }

    // ---- Col pass (off-diagonal tiles only): sim[j][i] = sim[i][j] ----
    if (bi != bj) {
        #pragma unroll
        for (int sj = 0; sj < 4; ++sj) {
            float s = 0.0f;
            #pragma unroll
            for (int si = 0; si < 4; ++si)
                #pragma unroll
                for (int r = 0; r < 4; ++r) s += acc[si][sj][r];
            s += __shfl_xor(s, 16);
            s += __shfl_xor(s, 32);
            if (quad == 0) {
                const int gcol = rowB0 + wc * 64 + sj * 16 + m;
                partials[(size_t)gcol * 128 + bi * 2 + wr] = s;
            }
        }
    }
}

// ---------------- Kernel 3: combine partials -> LSE; target dot; mean; last-block
//                  packs the output (fused former pack_out dispatch) --------------
__global__ __launch_bounds__(256) void combine_kernel(const float* __restrict__ partials,
                                                      const unsigned short* __restrict__ feats,
                                                      const int* __restrict__ y,
                                                      float* __restrict__ accum,
                                                      unsigned int* __restrict__ ticket,
                                                      unsigned int* __restrict__ out,
                                                      int nblocks) {
    __shared__ float red[4];
    const int wave = threadIdx.x >> 6;
    const int lane = threadIdx.x & 63;
    const int row  = blockIdx.x * 4 + wave;

    float L = partials[(size_t)row * 128 + lane] + partials[(size_t)row * 128 + 64 + lane];
    #pragma unroll
    for (int msk = 1; msk < 64; msk <<= 1) L += __shfl_xor(L, msk);
    float lse = INV_T + __logf(L);   // LSE = 1/T + log sum exp(l - 1/T)

    // target column c = y + (y >= row); dot(f_row, f_c) in bf16->fp32
    const int yv = y[row];
    const int c  = yv + (yv >= row ? 1 : 0);
    uint4 av = ((const uint4*)(feats + (size_t)row * ND))[lane];
    uint4 bv = ((const uint4*)(feats + (size_t)c   * ND))[lane];
    float dot = 0.0f;
    const unsigned int* au = (const unsigned int*)&av;
    const unsigned int* bu = (const unsigned int*)&bv;
    #pragma unroll
    for (int k = 0; k < 4; ++k) {
        dot += bf2f((unsigned short)(au[k] & 0xffffu)) * bf2f((unsigned short)(bu[k] & 0xffffu));
        dot += bf2f((unsigned short)(au[k] >> 16))     * bf2f((unsigned short)(bu[k] >> 16));
    }
    #pragma unroll
    for (int msk = 1; msk < 64; msk <<= 1) dot += __shfl_xor(dot, msk);

    float loss = lse - dot * INV_T;
    if (lane == 0) red[wave] = loss;
    __syncthreads();
    if (threadIdx.x == 0) {
        float s = red[0] + red[1] + red[2] + red[3];
        atomicAdd(accum, s * (1.0f / (float)NB));
        __threadfence();                       // my add visible before ticket bump
        unsigned int t = atomicAdd(ticket, 1u);
        if (t == (unsigned int)(nblocks - 1)) {
            float v = atomicAdd(accum, 0.0f);  // device-scope coherent read
            unsigned int b = f2bf(v);
            out[0] = (b << 16) | b;            // valid read as fp32 OR bf16
        }
    }
}

extern "C" void kernel_launch(void* const* d_in, const int* in_sizes, int n_in,
                              void* d_out, int out_size, void* d_ws, size_t ws_size,
                              hipStream_t stream) {
    const float* x = (const float*)d_in[0];
    const int*   y = (const int*)d_in[1];

    // ws: [0,8MB) bf16 feats; [8MB,12MB) float partials (8192x128); [12MB] accum; +4 ticket
    unsigned short* feats    = (unsigned short*)d_ws;
    float*          partials = (float*)((char*)d_ws + (size_t)8 * 1024 * 1024);
    float*          accum    = (float*)((char*)d_ws + (size_t)12 * 1024 * 1024);
    unsigned int*   ticket   = (unsigned int*)((char*)d_ws + (size_t)12 * 1024 * 1024 + 4);

    norm_kernel<<<NB / 4, 256, 0, stream>>>(x, feats, accum, ticket);
    const int ntiles = (NB / 128) * (NB / 128 + 1) / 2;   // 2080 upper-tri tiles
    sim_lse_kernel<<<ntiles, 256, 0, stream>>>(feats, partials);
    combine_kernel<<<NB / 4, 256, 0, stream>>>(partials, feats, y, accum, ticket,
                                               (unsigned int*)d_out, NB / 4);
}

// Round 4
// 162.273 us; speedup vs baseline: 1.1850x; 1.1850x over previous
//
#include <hip/hip_runtime.h>
#include <hip/hip_bf16.h>

// InfoNCE (n_views=1): loss = mean_i [ LSE_{j!=i}(f_i . f_j / T) - f_i . f_{c_i} / T ].
// Upper-triangle F F^T in FP8 (OCP e4m3) MFMA: non-scaled fp8 runs at the bf16
// rate but HALVES all LDS/global traffic (the measured bottleneck), and the
// 4 MB fp8 feats fit a single XCD L2. Fixed-max softmax partials (logit <= 1/T
// since rows are unit-norm). Target dot uses a bf16 copy for accuracy.

typedef float f32x4 __attribute__((ext_vector_type(4)));

#define AS1 __attribute__((address_space(1)))
#define AS3 __attribute__((address_space(3)))

constexpr int NB = 8192;   // batch
constexpr int ND = 512;    // dim
constexpr float INV_T = 1.0f / 0.07f;

__device__ inline unsigned short f2bf(float f) {
    union { float f; unsigned int u; } v; v.f = f;
    unsigned int u = v.u;
    u = u + 0x7fffu + ((u >> 16) & 1u);   // round-to-nearest-even
    return (unsigned short)(u >> 16);
}
__device__ inline float bf2f(unsigned short s) {
    union { unsigned int u; float f; } v; v.u = ((unsigned int)s) << 16;
    return v.f;
}

// ------- Kernel 1: normalize rows; write fp8 feats (GEMM) + bf16 feats (dot) -------
__global__ __launch_bounds__(256) void norm_kernel(const float* __restrict__ x,
                                                   unsigned char* __restrict__ feats8,
                                                   unsigned short* __restrict__ featsbf,
                                                   float* __restrict__ accum,
                                                   unsigned int* __restrict__ ticket) {
    if (blockIdx.x == 0 && threadIdx.x == 0) { accum[0] = 0.0f; ticket[0] = 0u; }
    const int wave = threadIdx.x >> 6;
    const int lane = threadIdx.x & 63;
    const int row  = blockIdx.x * 4 + wave;
    const float4* xr = (const float4*)(x + (size_t)row * ND);
    float4 a = xr[2 * lane];       // cols 8*lane   .. +3
    float4 b = xr[2 * lane + 1];   // cols 8*lane+4 .. +7
    float ss = a.x*a.x + a.y*a.y + a.z*a.z + a.w*a.w
             + b.x*b.x + b.y*b.y + b.z*b.z + b.w*b.w;
    #pragma unroll
    for (int m = 32; m >= 1; m >>= 1) ss += __shfl_xor(ss, m);
    float scale = 1.0f / fmaxf(sqrtf(ss), 1e-12f);
    a.x *= scale; a.y *= scale; a.z *= scale; a.w *= scale;
    b.x *= scale; b.y *= scale; b.z *= scale; b.w *= scale;

    // bf16 copy (contiguous 8 shorts per lane)
    uint4 ub;
    ub.x = (unsigned)f2bf(a.x) | ((unsigned)f2bf(a.y) << 16);
    ub.y = (unsigned)f2bf(a.z) | ((unsigned)f2bf(a.w) << 16);
    ub.z = (unsigned)f2bf(b.x) | ((unsigned)f2bf(b.y) << 16);
    ub.w = (unsigned)f2bf(b.z) | ((unsigned)f2bf(b.w) << 16);
    ((uint4*)(featsbf + (size_t)row * ND))[lane] = ub;

    // fp8 e4m3 copy (contiguous 8 bytes per lane)
    int w0 = __builtin_amdgcn_cvt_pk_fp8_f32(a.x, a.y, 0, false);
    w0     = __builtin_amdgcn_cvt_pk_fp8_f32(a.z, a.w, w0, true);
    int w1 = __builtin_amdgcn_cvt_pk_fp8_f32(b.x, b.y, 0, false);
    w1     = __builtin_amdgcn_cvt_pk_fp8_f32(b.z, b.w, w1, true);
    uint2 u8; u8.x = (unsigned)w0; u8.y = (unsigned)w1;
    ((uint2*)(feats8 + (size_t)row * ND))[lane] = u8;
}

// ------- Kernel 2: upper-tri 128x128 tiles, fp8 MFMA, fused fixed-max sumexp -------
// 2080 blocks -> (bi <= bj). 4 waves = 2x2 quadrants of 64x64. BK=128 fp8 bytes.
// LDS rows 128 B, XOR swizzle on 16B chunks (k8 ^= row&7) -> conflict-free.
__global__ __launch_bounds__(256) void sim_lse_kernel(const unsigned char* __restrict__ feats8,
                                                      float* __restrict__ partials) {
    __shared__ unsigned char sA[128 * 128];
    __shared__ unsigned char sB[128 * 128];

    const int tid  = threadIdx.x;
    const int lane = tid & 63;
    const int wave = tid >> 6;
    const int wr   = wave >> 1;     // wave row quadrant (0..1)
    const int wc   = wave & 1;      // wave col quadrant (0..1)

    // decode upper-triangle pair: t -> (bi <= bj)
    int t = blockIdx.x;
    int bj = (int)((sqrtf(8.0f * (float)t + 1.0f) - 1.0f) * 0.5f);
    while ((bj + 1) * (bj + 2) / 2 <= t) ++bj;
    while (bj * (bj + 1) / 2 > t) --bj;
    const int bi = t - bj * (bj + 1) / 2;

    const int rowA0 = bi * 128;
    const int rowB0 = bj * 128;

    f32x4 acc[4][4] = {};

    const int m     = lane & 15;
    const int quad  = lane >> 4;
    const int sw    = m & 7;          // ds_read swizzle (row & 7 == m & 7)
    const int half8 = (quad & 1) * 8; // low/high 8B of the 16B chunk

    for (int kt = 0; kt < 4; ++kt) {
        const int k0 = kt * 128;      // byte offset within the 512 B fp8 row
        #pragma unroll
        for (int r = 0; r < 4; ++r) {
            int c   = r * 256 + tid;  // 16B chunk id (1024 per array)
            int row = c >> 3;
            int k8g = (c & 7) ^ (row & 7);
            const unsigned char* ga = feats8 + (size_t)(rowA0 + row) * ND + k0 + k8g * 16;
            const unsigned char* gb = feats8 + (size_t)(rowB0 + row) * ND + k0 + k8g * 16;
            __builtin_amdgcn_global_load_lds((const AS1 void*)ga, (AS3 void*)(sA + c * 16), 16, 0, 0);
            __builtin_amdgcn_global_load_lds((const AS1 void*)gb, (AS3 void*)(sB + c * 16), 16, 0, 0);
        }
        __syncthreads();
        #pragma unroll
        for (int ks = 0; ks < 4; ++ks) {
            // lane's logical byte offset in row = ks*32 + quad*8
            const int cl = ks * 2 + (quad >> 1);   // logical 16B chunk
            long afr[4], bfr[4];
            #pragma unroll
            for (int s = 0; s < 4; ++s) {
                afr[s] = *(const long*)(sA + (wr * 64 + s * 16 + m) * 128 + ((cl ^ sw) << 4) + half8);
                bfr[s] = *(const long*)(sB + (wc * 64 + s * 16 + m) * 128 + ((cl ^ sw) << 4) + half8);
            }
            #pragma unroll
            for (int si = 0; si < 4; ++si)
                #pragma unroll
                for (int sj = 0; sj < 4; ++sj)
                    acc[si][sj] = __builtin_amdgcn_mfma_f32_16x16x32_fp8_fp8(
                        afr[si], bfr[sj], acc[si][sj], 0, 0, 0);
        }
        __syncthreads();
    }

    // ---- Transform in place: acc <- exp((sim-1)/T), diagonal -> 0 ----
    // C/D layout (16x16x32, dtype-independent): col = lane&15, row = quad*4 + reg.
    const float C1 = INV_T * 1.4426950408889634f;   // log2(e)/T
    #pragma unroll
    for (int si = 0; si < 4; ++si) {
        #pragma unroll
        for (int sj = 0; sj < 4; ++sj) {
            const int gcol = rowB0 + wc * 64 + sj * 16 + m;
            #pragma unroll
            for (int r = 0; r < 4; ++r) {
                const int grow = rowA0 + wr * 64 + si * 16 + quad * 4 + r;
                float e = exp2f(fmaf(acc[si][sj][r], C1, -C1));
                acc[si][sj][r] = (grow == gcol) ? 0.0f : e;
            }
        }
    }

    // ---- Row pass: per-row sumexp over this wave's 64 cols ----
    #pragma unroll
    for (int si = 0; si < 4; ++si) {
        #pragma unroll
        for (int r = 0; r < 4; ++r) {
            float s = acc[si][0][r] + acc[si][1][r] + acc[si][2][r] + acc[si][3][r];
            #pragma unroll
            for (int msk = 1; msk < 16; msk <<= 1) s += __shfl_xor(s, msk);
            if (m == 0) {
                const int grow = rowA0 + wr * 64 + si * 16 + quad * 4 + r;
                partials[(size_t)grow * 128 + bj * 2 + wc] = s;
            }
        }
    }

    // ---- Col pass (off-diagonal tiles only): sim[j][i] = sim[i][j] ----
    if (bi != bj) {
        #pragma unroll
        for (int sj = 0; sj < 4; ++sj) {
            float s = 0.0f;
            #pragma unroll
            for (int si = 0; si < 4; ++si)
                #pragma unroll
                for (int r = 0; r < 4; ++r) s += acc[si][sj][r];
            s += __shfl_xor(s, 16);
            s += __shfl_xor(s, 32);
            if (quad == 0) {
                const int gcol = rowB0 + wc * 64 + sj * 16 + m;
                partials[(size_t)gcol * 128 + bi * 2 + wr] = s;
            }
        }
    }
}

// ------- Kernel 3: combine partials -> LSE; target dot (bf16); mean; pack out -----
__global__ __launch_bounds__(256) void combine_kernel(const float* __restrict__ partials,
                                                      const unsigned short* __restrict__ featsbf,
                                                      const int* __restrict__ y,
                                                      float* __restrict__ accum,
                                                      unsigned int* __restrict__ ticket,
                                                      unsigned int* __restrict__ out,
                                                      int nblocks) {
    __shared__ float red[4];
    const int wave = threadIdx.x >> 6;
    const int lane = threadIdx.x & 63;
    const int row  = blockIdx.x * 4 + wave;

    float L = partials[(size_t)row * 128 + lane] + partials[(size_t)row * 128 + 64 + lane];
    #pragma unroll
    for (int msk = 1; msk < 64; msk <<= 1) L += __shfl_xor(L, msk);
    float lse = INV_T + __logf(L);   // LSE = 1/T + log sum exp(l - 1/T)

    // target column c = y + (y >= row); dot(f_row, f_c) in bf16->fp32
    const int yv = y[row];
    const int c  = yv + (yv >= row ? 1 : 0);
    uint4 av = ((const uint4*)(featsbf + (size_t)row * ND))[lane];
    uint4 bv = ((const uint4*)(featsbf + (size_t)c   * ND))[lane];
    float dot = 0.0f;
    const unsigned int* au = (const unsigned int*)&av;
    const unsigned int* bu = (const unsigned int*)&bv;
    #pragma unroll
    for (int k = 0; k < 4; ++k) {
        dot += bf2f((unsigned short)(au[k] & 0xffffu)) * bf2f((unsigned short)(bu[k] & 0xffffu));
        dot += bf2f((unsigned short)(au[k] >> 16))     * bf2f((unsigned short)(bu[k] >> 16));
    }
    #pragma unroll
    for (int msk = 1; msk < 64; msk <<= 1) dot += __shfl_xor(dot, msk);

    float loss = lse - dot * INV_T;
    if (lane == 0) red[wave] = loss;
    __syncthreads();
    if (threadIdx.x == 0) {
        float s = red[0] + red[1] + red[2] + red[3];
        atomicAdd(accum, s * (1.0f / (float)NB));
        __threadfence();                       // my add visible before ticket bump
        unsigned int t = atomicAdd(ticket, 1u);
        if (t == (unsigned int)(nblocks - 1)) {
            float v = atomicAdd(accum, 0.0f);  // device-scope coherent read
            unsigned int b = f2bf(v);
            out[0] = (b << 16) | b;            // valid read as fp32 OR bf16
        }
    }
}

extern "C" void kernel_launch(void* const* d_in, const int* in_sizes, int n_in,
                              void* d_out, int out_size, void* d_ws, size_t ws_size,
                              hipStream_t stream) {
    const float* x = (const float*)d_in[0];
    const int*   y = (const int*)d_in[1];

    // ws: [0,4M) fp8 feats; [4M,12M) bf16 feats; [12M,16M) float partials; [16M] accum+ticket
    unsigned char*  feats8   = (unsigned char*)d_ws;
    unsigned short* featsbf  = (unsigned short*)((char*)d_ws + (size_t)4 * 1024 * 1024);
    float*          partials = (float*)((char*)d_ws + (size_t)12 * 1024 * 1024);
    float*          accum    = (float*)((char*)d_ws + (size_t)16 * 1024 * 1024);
    unsigned int*   ticket   = (unsigned int*)((char*)d_ws + (size_t)16 * 1024 * 1024 + 4);

    norm_kernel<<<NB / 4, 256, 0, stream>>>(x, feats8, featsbf, accum, ticket);
    const int ntiles = (NB / 128) * (NB / 128 + 1) / 2;   // 2080 upper-tri tiles
    sim_lse_kernel<<<ntiles, 256, 0, stream>>>(feats8, partials);
    combine_kernel<<<NB / 4, 256, 0, stream>>>(partials, featsbf, y, accum, ticket,
                                               (unsigned int*)d_out, NB / 4);
}

// Round 5
// 114.090 us; speedup vs baseline: 1.6855x; 1.4223x over previous
//
#include <hip/hip_runtime.h>
#include <hip/hip_bf16.h>

// InfoNCE (n_views=1): loss = mean_i [ LSE_{j!=i}(f_i . f_j / T) - f_i . f_{c_i} / T ].
// FP8 (OCP e4m3) upper-triangle MFMA F F^T + fixed-max softmax partials.
// R4 fix: the per-block atomicAdd + __threadfence + ticket chain cost 59 us
// (2048 serialized same-address RMWs + cross-XCD L2-writeback fences).
// Replaced with plain per-block stores + a tiny final reduce dispatch.

typedef float f32x4 __attribute__((ext_vector_type(4)));

#define AS1 __attribute__((address_space(1)))
#define AS3 __attribute__((address_space(3)))

constexpr int NB = 8192;   // batch
constexpr int ND = 512;    // dim
constexpr int NBLK = NB / 4;   // combine blocks (4 rows each)
constexpr float INV_T = 1.0f / 0.07f;

__device__ inline unsigned short f2bf(float f) {
    union { float f; unsigned int u; } v; v.f = f;
    unsigned int u = v.u;
    u = u + 0x7fffu + ((u >> 16) & 1u);   // round-to-nearest-even
    return (unsigned short)(u >> 16);
}
__device__ inline float bf2f(unsigned short s) {
    union { unsigned int u; float f; } v; v.u = ((unsigned int)s) << 16;
    return v.f;
}

// ------- Kernel 1: normalize rows; write fp8 feats (GEMM) + bf16 feats (dot) -------
__global__ __launch_bounds__(256) void norm_kernel(const float* __restrict__ x,
                                                   unsigned char* __restrict__ feats8,
                                                   unsigned short* __restrict__ featsbf) {
    const int wave = threadIdx.x >> 6;
    const int lane = threadIdx.x & 63;
    const int row  = blockIdx.x * 4 + wave;
    const float4* xr = (const float4*)(x + (size_t)row * ND);
    float4 a = xr[2 * lane];       // cols 8*lane   .. +3
    float4 b = xr[2 * lane + 1];   // cols 8*lane+4 .. +7
    float ss = a.x*a.x + a.y*a.y + a.z*a.z + a.w*a.w
             + b.x*b.x + b.y*b.y + b.z*b.z + b.w*b.w;
    #pragma unroll
    for (int m = 32; m >= 1; m >>= 1) ss += __shfl_xor(ss, m);
    float scale = 1.0f / fmaxf(sqrtf(ss), 1e-12f);
    a.x *= scale; a.y *= scale; a.z *= scale; a.w *= scale;
    b.x *= scale; b.y *= scale; b.z *= scale; b.w *= scale;

    // bf16 copy (contiguous 8 shorts per lane)
    uint4 ub;
    ub.x = (unsigned)f2bf(a.x) | ((unsigned)f2bf(a.y) << 16);
    ub.y = (unsigned)f2bf(a.z) | ((unsigned)f2bf(a.w) << 16);
    ub.z = (unsigned)f2bf(b.x) | ((unsigned)f2bf(b.y) << 16);
    ub.w = (unsigned)f2bf(b.z) | ((unsigned)f2bf(b.w) << 16);
    ((uint4*)(featsbf + (size_t)row * ND))[lane] = ub;

    // fp8 e4m3 copy (contiguous 8 bytes per lane)
    int w0 = __builtin_amdgcn_cvt_pk_fp8_f32(a.x, a.y, 0, false);
    w0     = __builtin_amdgcn_cvt_pk_fp8_f32(a.z, a.w, w0, true);
    int w1 = __builtin_amdgcn_cvt_pk_fp8_f32(b.x, b.y, 0, false);
    w1     = __builtin_amdgcn_cvt_pk_fp8_f32(b.z, b.w, w1, true);
    uint2 u8; u8.x = (unsigned)w0; u8.y = (unsigned)w1;
    ((uint2*)(feats8 + (size_t)row * ND))[lane] = u8;
}

// ------- Kernel 2: upper-tri 128x128 tiles, fp8 MFMA, fused fixed-max sumexp -------
// 2080 blocks -> (bi <= bj). 4 waves = 2x2 quadrants of 64x64. BK=128 fp8 bytes.
// LDS rows 128 B, XOR swizzle on 16B chunks (k8 ^= row&7) -> conflict-free.
__global__ __launch_bounds__(256) void sim_lse_kernel(const unsigned char* __restrict__ feats8,
                                                      float* __restrict__ partials) {
    __shared__ unsigned char sA[128 * 128];
    __shared__ unsigned char sB[128 * 128];

    const int tid  = threadIdx.x;
    const int lane = tid & 63;
    const int wave = tid >> 6;
    const int wr   = wave >> 1;     // wave row quadrant (0..1)
    const int wc   = wave & 1;      // wave col quadrant (0..1)

    // decode upper-triangle pair: t -> (bi <= bj)
    int t = blockIdx.x;
    int bj = (int)((sqrtf(8.0f * (float)t + 1.0f) - 1.0f) * 0.5f);
    while ((bj + 1) * (bj + 2) / 2 <= t) ++bj;
    while (bj * (bj + 1) / 2 > t) --bj;
    const int bi = t - bj * (bj + 1) / 2;

    const int rowA0 = bi * 128;
    const int rowB0 = bj * 128;

    f32x4 acc[4][4] = {};

    const int m     = lane & 15;
    const int quad  = lane >> 4;
    const int sw    = m & 7;          // ds_read swizzle (row & 7 == m & 7)
    const int half8 = (quad & 1) * 8; // low/high 8B of the 16B chunk

    for (int kt = 0; kt < 4; ++kt) {
        const int k0 = kt * 128;      // byte offset within the 512 B fp8 row
        #pragma unroll
        for (int r = 0; r < 4; ++r) {
            int c   = r * 256 + tid;  // 16B chunk id (1024 per array)
            int row = c >> 3;
            int k8g = (c & 7) ^ (row & 7);
            const unsigned char* ga = feats8 + (size_t)(rowA0 + row) * ND + k0 + k8g * 16;
            const unsigned char* gb = feats8 + (size_t)(rowB0 + row) * ND + k0 + k8g * 16;
            __builtin_amdgcn_global_load_lds((const AS1 void*)ga, (AS3 void*)(sA + c * 16), 16, 0, 0);
            __builtin_amdgcn_global_load_lds((const AS1 void*)gb, (AS3 void*)(sB + c * 16), 16, 0, 0);
        }
        __syncthreads();
        #pragma unroll
        for (int ks = 0; ks < 4; ++ks) {
            // lane's logical byte offset in row = ks*32 + quad*8
            const int cl = ks * 2 + (quad >> 1);   // logical 16B chunk
            long afr[4], bfr[4];
            #pragma unroll
            for (int s = 0; s < 4; ++s) {
                afr[s] = *(const long*)(sA + (wr * 64 + s * 16 + m) * 128 + ((cl ^ sw) << 4) + half8);
                bfr[s] = *(const long*)(sB + (wc * 64 + s * 16 + m) * 128 + ((cl ^ sw) << 4) + half8);
            }
            #pragma unroll
            for (int si = 0; si < 4; ++si)
                #pragma unroll
                for (int sj = 0; sj < 4; ++sj)
                    acc[si][sj] = __builtin_amdgcn_mfma_f32_16x16x32_fp8_fp8(
                        afr[si], bfr[sj], acc[si][sj], 0, 0, 0);
        }
        __syncthreads();
    }

    // ---- Transform in place: acc <- exp((sim-1)/T), diagonal -> 0 ----
    // C/D layout (16x16x32, dtype-independent): col = lane&15, row = quad*4 + reg.
    const float C1 = INV_T * 1.4426950408889634f;   // log2(e)/T
    #pragma unroll
    for (int si = 0; si < 4; ++si) {
        #pragma unroll
        for (int sj = 0; sj < 4; ++sj) {
            const int gcol = rowB0 + wc * 64 + sj * 16 + m;
            #pragma unroll
            for (int r = 0; r < 4; ++r) {
                const int grow = rowA0 + wr * 64 + si * 16 + quad * 4 + r;
                float e = exp2f(fmaf(acc[si][sj][r], C1, -C1));
                acc[si][sj][r] = (grow == gcol) ? 0.0f : e;
            }
        }
    }

    // ---- Row pass: per-row sumexp over this wave's 64 cols ----
    #pragma unroll
    for (int si = 0; si < 4; ++si) {
        #pragma unroll
        for (int r = 0; r < 4; ++r) {
            float s = acc[si][0][r] + acc[si][1][r] + acc[si][2][r] + acc[si][3][r];
            #pragma unroll
            for (int msk = 1; msk < 16; msk <<= 1) s += __shfl_xor(s, msk);
            if (m == 0) {
                const int grow = rowA0 + wr * 64 + si * 16 + quad * 4 + r;
                partials[(size_t)grow * 128 + bj * 2 + wc] = s;
            }
        }
    }

    // ---- Col pass (off-diagonal tiles only): sim[j][i] = sim[i][j] ----
    if (bi != bj) {
        #pragma unroll
        for (int sj = 0; sj < 4; ++sj) {
            float s = 0.0f;
            #pragma unroll
            for (int si = 0; si < 4; ++si)
                #pragma unroll
                for (int r = 0; r < 4; ++r) s += acc[si][sj][r];
            s += __shfl_xor(s, 16);
            s += __shfl_xor(s, 32);
            if (quad == 0) {
                const int gcol = rowB0 + wc * 64 + sj * 16 + m;
                partials[(size_t)gcol * 128 + bi * 2 + wr] = s;
            }
        }
    }
}

// ------- Kernel 3: combine partials -> per-block loss sums (plain stores, no atomics)
__global__ __launch_bounds__(256) void combine_kernel(const float* __restrict__ partials,
                                                      const unsigned short* __restrict__ featsbf,
                                                      const int* __restrict__ y,
                                                      float* __restrict__ blockSums) {
    __shared__ float red[4];
    const int wave = threadIdx.x >> 6;
    const int lane = threadIdx.x & 63;
    const int row  = blockIdx.x * 4 + wave;

    float L = partials[(size_t)row * 128 + lane] + partials[(size_t)row * 128 + 64 + lane];
    #pragma unroll
    for (int msk = 1; msk < 64; msk <<= 1) L += __shfl_xor(L, msk);
    float lse = INV_T + __logf(L);   // LSE = 1/T + log sum exp(l - 1/T)

    // target column c = y + (y >= row); dot(f_row, f_c) in bf16->fp32
    const int yv = y[row];
    const int c  = yv + (yv >= row ? 1 : 0);
    uint4 av = ((const uint4*)(featsbf + (size_t)row * ND))[lane];
    uint4 bv = ((const uint4*)(featsbf + (size_t)c   * ND))[lane];
    float dot = 0.0f;
    const unsigned int* au = (const unsigned int*)&av;
    const unsigned int* bu = (const unsigned int*)&bv;
    #pragma unroll
    for (int k = 0; k < 4; ++k) {
        dot += bf2f((unsigned short)(au[k] & 0xffffu)) * bf2f((unsigned short)(bu[k] & 0xffffu));
        dot += bf2f((unsigned short)(au[k] >> 16))     * bf2f((unsigned short)(bu[k] >> 16));
    }
    #pragma unroll
    for (int msk = 1; msk < 64; msk <<= 1) dot += __shfl_xor(dot, msk);

    float loss = lse - dot * INV_T;
    if (lane == 0) red[wave] = loss;
    __syncthreads();
    if (threadIdx.x == 0)
        blockSums[blockIdx.x] = red[0] + red[1] + red[2] + red[3];
}

// ------- Kernel 4: single-block final reduce of 2048 block sums; pack output ------
__global__ __launch_bounds__(256) void finish_kernel(const float* __restrict__ blockSums,
                                                     unsigned int* __restrict__ out) {
    __shared__ float red[4];
    const int wave = threadIdx.x >> 6;
    const int lane = threadIdx.x & 63;
    float s = 0.0f;
    #pragma unroll
    for (int k = 0; k < NBLK / 256; ++k) s += blockSums[threadIdx.x + 256 * k];
    #pragma unroll
    for (int msk = 1; msk < 64; msk <<= 1) s += __shfl_xor(s, msk);
    if (lane == 0) red[wave] = s;
    __syncthreads();
    if (threadIdx.x == 0) {
        float v = (red[0] + red[1] + red[2] + red[3]) * (1.0f / (float)NB);
        unsigned int b = f2bf(v);
        out[0] = (b << 16) | b;   // valid read as fp32 OR bf16
    }
}

extern "C" void kernel_launch(void* const* d_in, const int* in_sizes, int n_in,
                              void* d_out, int out_size, void* d_ws, size_t ws_size,
                              hipStream_t stream) {
    const float* x = (const float*)d_in[0];
    const int*   y = (const int*)d_in[1];

    // ws: [0,4M) fp8 feats; [4M,12M) bf16 feats; [12M,16M) float partials; [16M..) blockSums
    unsigned char*  feats8    = (unsigned char*)d_ws;
    unsigned short* featsbf   = (unsigned short*)((char*)d_ws + (size_t)4 * 1024 * 1024);
    float*          partials  = (float*)((char*)d_ws + (size_t)12 * 1024 * 1024);
    float*          blockSums = (float*)((char*)d_ws + (size_t)16 * 1024 * 1024);

    norm_kernel<<<NB / 4, 256, 0, stream>>>(x, feats8, featsbf);
    const int ntiles = (NB / 128) * (NB / 128 + 1) / 2;   // 2080 upper-tri tiles
    sim_lse_kernel<<<ntiles, 256, 0, stream>>>(feats8, partials);
    combine_kernel<<<NBLK, 256, 0, stream>>>(partials, featsbf, y, blockSums);
    finish_kernel<<<1, 256, 0, stream>>>(blockSums, (unsigned int*)d_out);
}

// Round 7
// 110.633 us; speedup vs baseline: 1.7382x; 1.0312x over previous
//
#include <hip/hip_runtime.h>
#include <hip/hip_bf16.h>

// InfoNCE (n_views=1): loss = mean_i [ LSE_{j!=i}(f_i . f_j / T) - f_i . f_{c_i} / T ].
// FP8 (OCP e4m3) upper-triangle MFMA F F^T + fixed-max softmax partials.
// R6/R7: fp8 feats stored PRE-PERMUTED per 128-B K-window: 16-B unit U=ks2*4+q
// holds quad-q's 8-B fragments for k-steps 2ks2 and 2ks2+1. Staging (XOR-placed
// global_load_lds) unchanged; LDS reader is one ds_read_b128 per fragment PAIR,
// spanning all 32 banks per quarter-wave -> conflict-free, half the DS instrs
// (R5 had 4.26e6 conflicts = 2x LDS read cost). R6 bench died with a process-
// level abort (no absmax, no fault string) -> treated as infra-transient; code
// re-audited (bijection, bounds, alignment) and resubmitted unchanged.

typedef float f32x4 __attribute__((ext_vector_type(4)));
typedef long l2 __attribute__((ext_vector_type(2)));

#define AS1 __attribute__((address_space(1)))
#define AS3 __attribute__((address_space(3)))

constexpr int NB = 8192;   // batch
constexpr int ND = 512;    // dim
constexpr int NBLK = NB / 4;   // combine blocks (4 rows each)
constexpr float INV_T = 1.0f / 0.07f;

__device__ inline unsigned short f2bf(float f) {
    union { float f; unsigned int u; } v; v.f = f;
    unsigned int u = v.u;
    u = u + 0x7fffu + ((u >> 16) & 1u);   // round-to-nearest-even
    return (unsigned short)(u >> 16);
}
__device__ inline float bf2f(unsigned short s) {
    union { unsigned int u; float f; } v; v.u = ((unsigned int)s) << 16;
    return v.f;
}

// ------- Kernel 1: normalize rows; write PERMUTED fp8 feats + row-major bf16 -------
__global__ __launch_bounds__(256) void norm_kernel(const float* __restrict__ x,
                                                   unsigned char* __restrict__ feats8,
                                                   unsigned short* __restrict__ featsbf) {
    const int wave = threadIdx.x >> 6;
    const int lane = threadIdx.x & 63;
    const int row  = blockIdx.x * 4 + wave;
    const float4* xr = (const float4*)(x + (size_t)row * ND);
    float4 a = xr[2 * lane];       // cols 8*lane   .. +3
    float4 b = xr[2 * lane + 1];   // cols 8*lane+4 .. +7
    float ss = a.x*a.x + a.y*a.y + a.z*a.z + a.w*a.w
             + b.x*b.x + b.y*b.y + b.z*b.z + b.w*b.w;
    #pragma unroll
    for (int m = 32; m >= 1; m >>= 1) ss += __shfl_xor(ss, m);
    float scale = 1.0f / fmaxf(sqrtf(ss), 1e-12f);
    a.x *= scale; a.y *= scale; a.z *= scale; a.w *= scale;
    b.x *= scale; b.y *= scale; b.z *= scale; b.w *= scale;

    // bf16 copy, row-major (contiguous 8 shorts per lane) — used by combine's dot
    uint4 ub;
    ub.x = (unsigned)f2bf(a.x) | ((unsigned)f2bf(a.y) << 16);
    ub.y = (unsigned)f2bf(a.z) | ((unsigned)f2bf(a.w) << 16);
    ub.z = (unsigned)f2bf(b.x) | ((unsigned)f2bf(b.y) << 16);
    ub.w = (unsigned)f2bf(b.z) | ((unsigned)f2bf(b.w) << 16);
    ((uint4*)(featsbf + (size_t)row * ND))[lane] = ub;

    // fp8 e4m3, PERMUTED: lane holds original 8-B piece L (k = 8L..8L+7), i.e.
    // kt = L>>4, ks = (L>>2)&3, q = L&3.  New 8-B slot within the row:
    //   slot = kt*16 + (ks2*4 + q)*2 + (ks&1),  ks2 = ks>>1
    int w0 = __builtin_amdgcn_cvt_pk_fp8_f32(a.x, a.y, 0, false);
    w0     = __builtin_amdgcn_cvt_pk_fp8_f32(a.z, a.w, w0, true);
    int w1 = __builtin_amdgcn_cvt_pk_fp8_f32(b.x, b.y, 0, false);
    w1     = __builtin_amdgcn_cvt_pk_fp8_f32(b.z, b.w, w1, true);
    uint2 u8; u8.x = (unsigned)w0; u8.y = (unsigned)w1;
    const int L    = lane;
    const int slot = ((L >> 4) << 4) + ((((L >> 3) & 1) * 4 + (L & 3)) << 1) + ((L >> 2) & 1);
    ((uint2*)(feats8 + (size_t)row * ND))[slot] = u8;
}

// ------- Kernel 2: upper-tri 128x128 tiles, fp8 MFMA, fused fixed-max sumexp -------
// 2080 blocks -> (bi <= bj). 4 waves = 2x2 quadrants of 64x64. BK=128 fp8 bytes.
// LDS(r, u) = G(r, kt, u ^ (r&7)); reader fetches unit (ks2*4+q)^(r&7) as b128:
// low 8 B = k-step 2ks2 fragment, high 8 B = k-step 2ks2+1. Conflict-free.
__global__ __launch_bounds__(256) void sim_lse_kernel(const unsigned char* __restrict__ feats8,
                                                      float* __restrict__ partials) {
    __shared__ unsigned char sA[128 * 128];
    __shared__ unsigned char sB[128 * 128];

    const int tid  = threadIdx.x;
    const int lane = tid & 63;
    const int wave = tid >> 6;
    const int wr   = wave >> 1;     // wave row quadrant (0..1)
    const int wc   = wave & 1;      // wave col quadrant (0..1)

    // decode upper-triangle pair: t -> (bi <= bj)
    int t = blockIdx.x;
    int bj = (int)((sqrtf(8.0f * (float)t + 1.0f) - 1.0f) * 0.5f);
    while ((bj + 1) * (bj + 2) / 2 <= t) ++bj;
    while (bj * (bj + 1) / 2 > t) --bj;
    const int bi = t - bj * (bj + 1) / 2;

    const int rowA0 = bi * 128;
    const int rowB0 = bj * 128;

    f32x4 acc[4][4] = {};

    const int m    = lane & 15;
    const int quad = lane >> 4;
    const int sw   = m & 7;         // unit swizzle (row & 7 == m & 7)

    for (int kt = 0; kt < 4; ++kt) {
        const int k0 = kt * 128;      // byte offset within the 512 B fp8 row
        #pragma unroll
        for (int r = 0; r < 4; ++r) {
            int c   = r * 256 + tid;  // 16B chunk id (1024 per array)
            int row = c >> 3;
            int k8g = (c & 7) ^ (row & 7);
            const unsigned char* ga = feats8 + (size_t)(rowA0 + row) * ND + k0 + k8g * 16;
            const unsigned char* gb = feats8 + (size_t)(rowB0 + row) * ND + k0 + k8g * 16;
            __builtin_amdgcn_global_load_lds((const AS1 void*)ga, (AS3 void*)(sA + c * 16), 16, 0, 0);
            __builtin_amdgcn_global_load_lds((const AS1 void*)gb, (AS3 void*)(sB + c * 16), 16, 0, 0);
        }
        __syncthreads();
        #pragma unroll
        for (int ks2 = 0; ks2 < 2; ++ks2) {
            const int uoff = ((ks2 * 4 + quad) ^ sw) << 4;   // swizzled 16B unit
            l2 afr[4], bfr[4];
            #pragma unroll
            for (int s = 0; s < 4; ++s) {
                afr[s] = *(const l2*)(sA + (wr * 64 + s * 16 + m) * 128 + uoff);
                bfr[s] = *(const l2*)(sB + (wc * 64 + s * 16 + m) * 128 + uoff);
            }
            #pragma unroll
            for (int e = 0; e < 2; ++e)
                #pragma unroll
                for (int si = 0; si < 4; ++si)
                    #pragma unroll
                    for (int sj = 0; sj < 4; ++sj)
                        acc[si][sj] = __builtin_amdgcn_mfma_f32_16x16x32_fp8_fp8(
                            afr[si][e], bfr[sj][e], acc[si][sj], 0, 0, 0);
        }
        __syncthreads();
    }

    // ---- Transform in place: acc <- exp((sim-1)/T), diagonal -> 0 ----
    // C/D layout (16x16x32, dtype-independent): col = lane&15, row = quad*4 + reg.
    const float C1 = INV_T * 1.4426950408889634f;   // log2(e)/T
    #pragma unroll
    for (int si = 0; si < 4; ++si) {
        #pragma unroll
        for (int sj = 0; sj < 4; ++sj) {
            const int gcol = rowB0 + wc * 64 + sj * 16 + m;
            #pragma unroll
            for (int r = 0; r < 4; ++r) {
                const int grow = rowA0 + wr * 64 + si * 16 + quad * 4 + r;
                float e = exp2f(fmaf(acc[si][sj][r], C1, -C1));
                acc[si][sj][r] = (grow == gcol) ? 0.0f : e;
            }
        }
    }

    // ---- Row pass: per-row sumexp over this wave's 64 cols ----
    #pragma unroll
    for (int si = 0; si < 4; ++si) {
        #pragma unroll
        for (int r = 0; r < 4; ++r) {
            float s = acc[si][0][r] + acc[si][1][r] + acc[si][2][r] + acc[si][3][r];
            #pragma unroll
            for (int msk = 1; msk < 16; msk <<= 1) s += __shfl_xor(s, msk);
            if (m == 0) {
                const int grow = rowA0 + wr * 64 + si * 16 + quad * 4 + r;
                partials[(size_t)grow * 128 + bj * 2 + wc] = s;
            }
        }
    }

    // ---- Col pass (off-diagonal tiles only): sim[j][i] = sim[i][j] ----
    if (bi != bj) {
        #pragma unroll
        for (int sj = 0; sj < 4; ++sj) {
            float s = 0.0f;
            #pragma unroll
            for (int si = 0; si < 4; ++si)
                #pragma unroll
                for (int r = 0; r < 4; ++r) s += acc[si][sj][r];
            s += __shfl_xor(s, 16);
            s += __shfl_xor(s, 32);
            if (quad == 0) {
                const int gcol = rowB0 + wc * 64 + sj * 16 + m;
                partials[(size_t)gcol * 128 + bi * 2 + wr] = s;
            }
        }
    }
}

// ------- Kernel 3: combine partials -> per-block loss sums (plain stores, no atomics)
__global__ __launch_bounds__(256) void combine_kernel(const float* __restrict__ partials,
                                                      const unsigned short* __restrict__ featsbf,
                                                      const int* __restrict__ y,
                                                      float* __restrict__ blockSums) {
    __shared__ float red[4];
    const int wave = threadIdx.x >> 6;
    const int lane = threadIdx.x & 63;
    const int row  = blockIdx.x * 4 + wave;

    float L = partials[(size_t)row * 128 + lane] + partials[(size_t)row * 128 + 64 + lane];
    #pragma unroll
    for (int msk = 1; msk < 64; msk <<= 1) L += __shfl_xor(L, msk);
    float lse = INV_T + __logf(L);   // LSE = 1/T + log sum exp(l - 1/T)

    // target column c = y + (y >= row); dot(f_row, f_c) in bf16->fp32
    const int yv = y[row];
    const int c  = yv + (yv >= row ? 1 : 0);
    uint4 av = ((const uint4*)(featsbf + (size_t)row * ND))[lane];
    uint4 bv = ((const uint4*)(featsbf + (size_t)c   * ND))[lane];
    float dot = 0.0f;
    const unsigned int* au = (const unsigned int*)&av;
    const unsigned int* bu = (const unsigned int*)&bv;
    #pragma unroll
    for (int k = 0; k < 4; ++k) {
        dot += bf2f((unsigned short)(au[k] & 0xffffu)) * bf2f((unsigned short)(bu[k] & 0xffffu));
        dot += bf2f((unsigned short)(au[k] >> 16))     * bf2f((unsigned short)(bu[k] >> 16));
    }
    #pragma unroll
    for (int msk = 1; msk < 64; msk <<= 1) dot += __shfl_xor(dot, msk);

    float loss = lse - dot * INV_T;
    if (lane == 0) red[wave] = loss;
    __syncthreads();
    if (threadIdx.x == 0)
        blockSums[blockIdx.x] = red[0] + red[1] + red[2] + red[3];
}

// ------- Kernel 4: single-block final reduce of 2048 block sums; pack output ------
__global__ __launch_bounds__(256) void finish_kernel(const float* __restrict__ blockSums,
                                                     unsigned int* __restrict__ out) {
    __shared__ float red[4];
    const int wave = threadIdx.x >> 6;
    const int lane = threadIdx.x & 63;
    float s = 0.0f;
    #pragma unroll
    for (int k = 0; k < NBLK / 256; ++k) s += blockSums[threadIdx.x + 256 * k];
    #pragma unroll
    for (int msk = 1; msk < 64; msk <<= 1) s += __shfl_xor(s, msk);
    if (lane == 0) red[wave] = s;
    __syncthreads();
    if (threadIdx.x == 0) {
        float v = (red[0] + red[1] + red[2] + red[3]) * (1.0f / (float)NB);
        unsigned int b = f2bf(v);
        out[0] = (b << 16) | b;   // valid read as fp32 OR bf16
    }
}

extern "C" void kernel_launch(void* const* d_in, const int* in_sizes, int n_in,
                              void* d_out, int out_size, void* d_ws, size_t ws_size,
                              hipStream_t stream) {
    const float* x = (const float*)d_in[0];
    const int*   y = (const int*)d_in[1];

    // ws: [0,4M) fp8 feats (permuted); [4M,12M) bf16 feats; [12M,16M) partials; [16M..) blockSums
    unsigned char*  feats8    = (unsigned char*)d_ws;
    unsigned short* featsbf   = (unsigned short*)((char*)d_ws + (size_t)4 * 1024 * 1024);
    float*          partials  = (float*)((char*)d_ws + (size_t)12 * 1024 * 1024);
    float*          blockSums = (float*)((char*)d_ws + (size_t)16 * 1024 * 1024);

    norm_kernel<<<NB / 4, 256, 0, stream>>>(x, feats8, featsbf);
    const int ntiles = (NB / 128) * (NB / 128 + 1) / 2;   // 2080 upper-tri tiles
    sim_lse_kernel<<<ntiles, 256, 0, stream>>>(feats8, partials);
    combine_kernel<<<NBLK, 256, 0, stream>>>(partials, featsbf, y, blockSums);
    finish_kernel<<<1, 256, 0, stream>>>(blockSums, (unsigned int*)d_out);
}